// Round 9
// baseline (9748.415 us; speedup 1.0000x reference)
//
#include <hip/hip_runtime.h>

#define SEQ 512
#define BATCH 32
#define NTAG 12
#define STOP_TAG 11

typedef __attribute__((ext_vector_type(4))) float f32x4;

static __device__ __forceinline__ float sigm(float x) {
  return 1.0f / (1.0f + __expf(-x));
}
static __device__ __forceinline__ float tanh_fast(float x) {
  // exact identity: tanh(x) = 1 - 2/(exp(2x)+1); error only from __expf ulp
  return 1.0f - 2.0f / (1.0f + __expf(2.0f * x));
}

// ---------------- embedding gather: x0[s*32+b][e] = emb[inputs[b][s]][e] ----------------
__global__ __launch_bounds__(64) void embed_kernel(const int* __restrict__ inputs,
                                                   const float* __restrict__ emb,
                                                   float* __restrict__ x0) {
  const int sb = blockIdx.x;          // s*32 + b
  const int s = sb >> 5, b = sb & 31;
  const int tok = inputs[b * SEQ + s];
  const float4* src = (const float4*)(emb + (size_t)tok * 256);
  float4* dst = (float4*)(x0 + (size_t)sb * 256);
  dst[threadIdx.x] = src[threadIdx.x];
}

// ---------------- generic fp32 GEMM: C[M][N] = A[M][K] @ W[N][K]^T (+b1+b2) ----------------
__global__ __launch_bounds__(256) void gemm_nt(const float* __restrict__ A,
                                               const float* __restrict__ W,
                                               const float* __restrict__ b1,
                                               const float* __restrict__ b2,
                                               float* __restrict__ C,
                                               int M, int N, int K, int ldc) {
  __shared__ float aT[16][68];
  __shared__ float wT[16][68];
  const int tid = threadIdx.x;
  const int bm = blockIdx.x * 64;
  const int bn = blockIdx.y * 64;
  const int tm = ((tid >> 4) & 15) << 2;
  const int tn = (tid & 15) << 2;
  const int lr = tid >> 2;
  const int lk = (tid & 3) << 2;
  const bool wok = (bn + lr) < N;
  float acc00 = 0.f, acc01 = 0.f, acc02 = 0.f, acc03 = 0.f;
  float acc10 = 0.f, acc11 = 0.f, acc12 = 0.f, acc13 = 0.f;
  float acc20 = 0.f, acc21 = 0.f, acc22 = 0.f, acc23 = 0.f;
  float acc30 = 0.f, acc31 = 0.f, acc32 = 0.f, acc33 = 0.f;
  for (int k0 = 0; k0 < K; k0 += 16) {
    float4 av = *(const float4*)(A + (size_t)(bm + lr) * K + k0 + lk);
    float4 wv = make_float4(0.f, 0.f, 0.f, 0.f);
    if (wok) wv = *(const float4*)(W + (size_t)(bn + lr) * K + k0 + lk);
    aT[lk + 0][lr] = av.x; aT[lk + 1][lr] = av.y; aT[lk + 2][lr] = av.z; aT[lk + 3][lr] = av.w;
    wT[lk + 0][lr] = wv.x; wT[lk + 1][lr] = wv.y; wT[lk + 2][lr] = wv.z; wT[lk + 3][lr] = wv.w;
    __syncthreads();
#pragma unroll
    for (int k = 0; k < 16; ++k) {
      float4 a4 = *(const float4*)&aT[k][tm];
      float4 w4 = *(const float4*)&wT[k][tn];
      acc00 += a4.x * w4.x; acc01 += a4.x * w4.y; acc02 += a4.x * w4.z; acc03 += a4.x * w4.w;
      acc10 += a4.y * w4.x; acc11 += a4.y * w4.y; acc12 += a4.y * w4.z; acc13 += a4.y * w4.w;
      acc20 += a4.z * w4.x; acc21 += a4.z * w4.y; acc22 += a4.z * w4.z; acc23 += a4.z * w4.w;
      acc30 += a4.w * w4.x; acc31 += a4.w * w4.y; acc32 += a4.w * w4.z; acc33 += a4.w * w4.w;
    }
    __syncthreads();
  }
  float r[4][4] = {{acc00, acc01, acc02, acc03},
                   {acc10, acc11, acc12, acc13},
                   {acc20, acc21, acc22, acc23},
                   {acc30, acc31, acc32, acc33}};
#pragma unroll
  for (int i = 0; i < 4; ++i) {
#pragma unroll
    for (int j = 0; j < 4; ++j) {
      int n = bn + tn + j;
      if (n < N) {
        float v = r[i][j];
        if (b1) v += b1[n];
        if (b2) v += b2[n];
        C[(size_t)(bm + tm + i) * ldc + n] = v;
      }
    }
  }
}

// ---------------- 4-way-split BiLSTM scan with self-tagging exchange ----------------
// grid = 256. bid = q*64 + pair; bid%8 == pair%8 so quarters share an XCD under the %8
// round-robin. Weights register-resident via LDS bounce (R5). Exchange: band-tagged
// values (R7): producer stores h + 2*(t&3); consumers poll the data itself.
// R9 poll restructure: (1) np prefetch issued AFTER the poll barrier (in-order vmcnt
// drain no longer serializes an HBM load into the sync chain); (2) 48 b128 pollers
// (4 values each, per-dword band check rejects partial visibility); (3) pollers on
// wave 3 (no outstanding gate stores -> clean vmcnt(0)); (4) tight spin, fallback to
// agent-scope + sleep after 32 spins (wrong-XCD mapping degrades to slow, never hangs).
__global__ __launch_bounds__(256, 1) void lstm_scan(const float* __restrict__ pre_f,
                                                    const float* __restrict__ pre_b,
                                                    const float* __restrict__ whh_f,
                                                    const float* __restrict__ whh_b,
                                                    float* __restrict__ hs,   // [SEQ*32][512]
                                                    float* __restrict__ hx) { // [64][2][256], NaN-init
  const int bid = blockIdx.x;
  const int pair = bid & 63;
  const int q = bid >> 6;
  const int dir = pair >> 5;
  const int b = pair & 31;
  const float* __restrict__ pre = dir ? pre_b : pre_f;
  const float* __restrict__ whh = dir ? whh_b : whh_f;
  const int tid = threadIdx.x;
  const int u = tid & 63;
  const int col = (tid >> 6) * 256 + (q << 6) + u;
  float* hx_w = hx + pair * 512;                    // [2][256]

  __shared__ float4 stage[8192];   // 128 KB staging, clobbered between rounds
  __shared__ float hbuf[2][256];
  __shared__ float zbuf[256];

  // ---- LDS bounce, round 0: k in [0,128) ----
  for (int it = 0; it < 32; ++it) {
    const int id = (it << 8) + tid;
    const int lc = id >> 5;          // local col 0..255
    const int g = id & 31;
    const int gcol = ((lc >> 6) << 8) + (q << 6) + (lc & 63);
    stage[(lc << 5) | (g ^ (lc & 31))] = *((const float4*)(whh + (size_t)gcol * 256) + g);
  }
  __syncthreads();
  float4 wv[64];
#pragma unroll
  for (int g = 0; g < 32; ++g)
    wv[g] = stage[(tid << 5) | (g ^ (tid & 31))];
  __syncthreads();
  // ---- round 1: k in [128,256) overwrites the staging buffer ----
  for (int it = 0; it < 32; ++it) {
    const int id = (it << 8) + tid;
    const int lc = id >> 5;
    const int g = id & 31;
    const int gcol = ((lc >> 6) << 8) + (q << 6) + (lc & 63);
    stage[(lc << 5) | (g ^ (lc & 31))] = *((const float4*)(whh + (size_t)gcol * 256) + 32 + g);
  }
  __syncthreads();
#pragma unroll
  for (int g = 0; g < 32; ++g)
    wv[32 + g] = stage[(tid << 5) | (g ^ (tid & 31))];

  hbuf[0][tid] = 0.0f;
  hbuf[1][tid] = 0.0f;
  float c_reg = 0.0f;               // thread tid<64 owns cell state of unit q*64+tid
  const int sfirst = dir ? (SEQ - 1) : 0;
  float p = pre[((size_t)(sfirst * BATCH) + b) * 1024 + col];
  __syncthreads();

  for (int t = 0; t < SEQ; ++t) {
    const int s = dir ? (SEQ - 1 - t) : t;
    if (t > 0) {
      if (tid >= 192 && tid < 240) {  // wave 3: 48 pollers, b128 each (4 peer values)
        const int local = tid - 192;
        const int pi = local >> 4;              // 0..2
        const int pq = (q + 1 + pi) & 3;        // peer quarter
        const int f4 = (pq << 4) + (local & 15);
        const float ef = 2.0f * (float)((t - 1) & 3);
        const float* addr = hx_w + ((t - 1) & 1) * 256 + f4 * 4;
        f32x4 v;
        int spin = 0;
        while (true) {
          if (spin < 32) {
            // L1-bypass L2-served b128 (XCD-local fast path); drains only this wave's vmem
            asm volatile("global_load_dwordx4 %0, %1, off sc0\n\t"
                         "s_waitcnt vmcnt(0)"
                         : "=v"(v) : "v"(addr));
          } else {
            // LLC fallback: guaranteed to observe the write-through store
            v.x = __hip_atomic_load(addr + 0, __ATOMIC_RELAXED, __HIP_MEMORY_SCOPE_AGENT);
            v.y = __hip_atomic_load(addr + 1, __ATOMIC_RELAXED, __HIP_MEMORY_SCOPE_AGENT);
            v.z = __hip_atomic_load(addr + 2, __ATOMIC_RELAXED, __HIP_MEMORY_SCOPE_AGENT);
            v.w = __hip_atomic_load(addr + 3, __ATOMIC_RELAXED, __HIP_MEMORY_SCOPE_AGENT);
          }
          const bool ok = (__builtin_fabsf(v.x - ef) <= 1.0f) &
                          (__builtin_fabsf(v.y - ef) <= 1.0f) &
                          (__builtin_fabsf(v.z - ef) <= 1.0f) &
                          (__builtin_fabsf(v.w - ef) <= 1.0f);  // NaN/stale/partial rejected
          if (ok) break;
          ++spin;
          if (spin >= 32) __builtin_amdgcn_s_sleep(1);
        }
        *(float4*)&hbuf[t & 1][f4 * 4] =
            make_float4(v.x - ef, v.y - ef, v.z - ef, v.w - ef);  // exact (Sterbenz)
      }
      __syncthreads();
    }
    // np prefetch issued AFTER the poll barrier: in flight across FMA+gate (~1500 cy),
    // never inside the poll drain. Consumed at next step's FMA.
    float np = 0.0f;
    if (t + 1 < SEQ) {
      const int sn = dir ? (s - 1) : (s + 1);
      np = pre[((size_t)(sn * BATCH) + b) * 1024 + col];
    }
    // z[col] = pre + sum_k h[k] * whh[col][k]; 4-way acc split breaks the FMA chain
    float a0 = p, a1 = 0.f, a2 = 0.f, a3 = 0.f;
    const float4* hb = (const float4*)hbuf[t & 1];
#pragma unroll
    for (int g = 0; g < 64; ++g) {
      const float4 h4 = hb[g];      // LDS broadcast
      a0 = fmaf(h4.x, wv[g].x, a0);
      a1 = fmaf(h4.y, wv[g].y, a1);
      a2 = fmaf(h4.z, wv[g].z, a2);
      a3 = fmaf(h4.w, wv[g].w, a3);
    }
    zbuf[tid] = (a0 + a1) + (a2 + a3);
    __syncthreads();
    if (tid < 64) {                 // wave 0: gate combine for unit q*64+u
      const float zi = zbuf[u];
      const float zf = zbuf[64 + u];
      const float zg = zbuf[128 + u];
      const float zo = zbuf[192 + u];
      c_reg = sigm(zf) * c_reg + sigm(zi) * tanh_fast(zg);
      const float h = sigm(zo) * tanh_fast(c_reg);
      // exchange-critical store FIRST (leads the store queue)
      __hip_atomic_store(hx_w + (t & 1) * 256 + (q << 6) + u, h + 2.0f * (float)(t & 3),
                         __ATOMIC_RELAXED, __HIP_MEMORY_SCOPE_AGENT);
      hbuf[(t + 1) & 1][(q << 6) + u] = h;   // ordered before peers' reads by next poll-barrier
      hs[((size_t)(s * BATCH) + b) * 512 + dir * 256 + (q << 6) + u] = h;
    }
    // no trailing barrier: next iteration's poll-__syncthreads orders zbuf/hbuf reuse
    p = np;
  }
}

// ---------------- attention: per time-step s, scores over the batch dim ----------------
__global__ __launch_bounds__(256) void attention_kernel(const float* __restrict__ h1s,
                                                        float* __restrict__ att) {
  const int s = blockIdx.x;
  __shared__ float wl[32][512];   // w rows
  __shared__ float xT[512][36];   // x transposed
  __shared__ float sc[32][33];    // scores / weights
  const int tid = threadIdx.x;
#pragma unroll
  for (int r = 0; r < 16; ++r) {
    int flat = r * 1024 + tid * 4;
    int bb = flat >> 9;
    int d = flat & 511;
    float4 wv = *(const float4*)(att + ((size_t)(s * BATCH) + bb) * 1024 + d);
    *(float4*)&wl[bb][d] = wv;
    float4 xv = *(const float4*)(h1s + ((size_t)(s * BATCH) + bb) * 512 + d);
    xT[d + 0][bb] = xv.x; xT[d + 1][bb] = xv.y; xT[d + 2][bb] = xv.z; xT[d + 3][bb] = xv.w;
  }
  __syncthreads();
  {
    const int i = tid >> 3;
    const int j0 = (tid & 7) << 2;
    float a0 = 0.f, a1 = 0.f, a2 = 0.f, a3 = 0.f;
    for (int k = 0; k < 512; ++k) {
      float wv = wl[i][k];
      float4 x4 = *(const float4*)&xT[k][j0];
      a0 += wv * x4.x; a1 += wv * x4.y; a2 += wv * x4.z; a3 += wv * x4.w;
    }
    sc[i][j0 + 0] = a0; sc[i][j0 + 1] = a1; sc[i][j0 + 2] = a2; sc[i][j0 + 3] = a3;
  }
  __syncthreads();
  if (tid < 32) {
    float m = -3.4e38f;
    for (int j = 0; j < 32; ++j) m = fmaxf(m, sc[tid][j]);
    float sum = 0.f;
    for (int j = 0; j < 32; ++j) { float ev = __expf(sc[tid][j] - m); sc[tid][j] = ev; sum += ev; }
    float inv = 1.0f / sum;
    for (int j = 0; j < 32; ++j) sc[tid][j] *= inv;
  }
  __syncthreads();
  {
    const int i = tid >> 3;
    const int dq = tid & 7;
#pragma unroll
    for (int rep = 0; rep < 8; ++rep) {
      const int d0 = dq * 64 + rep * 8;
      float g0 = 0.f, g1 = 0.f, g2 = 0.f, g3 = 0.f, g4 = 0.f, g5 = 0.f, g6 = 0.f, g7 = 0.f;
      for (int j = 0; j < 32; ++j) {
        float wt = sc[i][j];
        g0 += wt * xT[d0 + 0][j]; g1 += wt * xT[d0 + 1][j];
        g2 += wt * xT[d0 + 2][j]; g3 += wt * xT[d0 + 3][j];
        g4 += wt * xT[d0 + 4][j]; g5 += wt * xT[d0 + 5][j];
        g6 += wt * xT[d0 + 6][j]; g7 += wt * xT[d0 + 7][j];
      }
      float* o = att + ((size_t)(s * BATCH) + i) * 1024 + 512 + d0;
      *(float4*)(o) = make_float4(g0, g1, g2, g3);
      *(float4*)(o + 4) = make_float4(g4, g5, g6, g7);
    }
  }
}

// ---------------- Viterbi decode: one block per batch element ----------------
__global__ __launch_bounds__(64) void viterbi_kernel(const float* __restrict__ feats,
                                                     const float* __restrict__ trans,
                                                     int* __restrict__ out) {
  const int b = blockIdx.x;
  __shared__ float tl[NTAG][NTAG];
  __shared__ float fv[2][NTAG];
  __shared__ unsigned char bp[SEQ][NTAG];
  const int tid = threadIdx.x;
  for (int i = tid; i < NTAG * NTAG; i += 64) tl[i / NTAG][i % NTAG] = trans[i];
  if (tid < NTAG) fv[0][tid] = (tid == 10) ? 0.f : -10000.f;
  __syncthreads();
  for (int t = 0; t < SEQ; ++t) {
    const int cur = t & 1;
    if (tid < NTAG) {
      float m = -3.4e38f;
      int arg = 0;
      for (int p = 0; p < NTAG; ++p) {
        float v = fv[cur][p] + tl[tid][p];
        if (v > m) { m = v; arg = p; }   // strict > == first-max (matches jnp.argmax)
      }
      bp[t][tid] = (unsigned char)arg;
      fv[cur ^ 1][tid] = m + feats[((size_t)t * BATCH + b) * NTAG + tid];
    }
    __syncthreads();
  }
  if (tid == 0) {
    float m = -3.4e38f;
    int tag = 0;
    for (int p = 0; p < NTAG; ++p) {
      float v = fv[0][p] + tl[STOP_TAG][p];
      if (v > m) { m = v; tag = p; }
    }
    for (int t = SEQ - 1; t >= 0; --t) {
      out[b * SEQ + t] = tag;
      tag = bp[t][tag];
    }
  }
}

// ---------------- launch ----------------
extern "C" void kernel_launch(void* const* d_in, const int* in_sizes, int n_in,
                              void* d_out, int out_size, void* d_ws, size_t ws_size,
                              hipStream_t stream) {
  const int* inputs = (const int*)d_in[0];
  const float* emb = (const float*)d_in[1];
  const float* w1f_ih = (const float*)d_in[2];
  const float* w1f_hh = (const float*)d_in[3];
  const float* b1f_ih = (const float*)d_in[4];
  const float* b1f_hh = (const float*)d_in[5];
  const float* w1b_ih = (const float*)d_in[6];
  const float* w1b_hh = (const float*)d_in[7];
  const float* b1b_ih = (const float*)d_in[8];
  const float* b1b_hh = (const float*)d_in[9];
  const float* attW = (const float*)d_in[10];
  const float* w2f_ih = (const float*)d_in[11];
  const float* w2f_hh = (const float*)d_in[12];
  const float* b2f_ih = (const float*)d_in[13];
  const float* b2f_hh = (const float*)d_in[14];
  const float* w2b_ih = (const float*)d_in[15];
  const float* w2b_hh = (const float*)d_in[16];
  const float* b2b_ih = (const float*)d_in[17];
  const float* b2b_hh = (const float*)d_in[18];
  const float* h2t_W = (const float*)d_in[19];
  const float* h2t_b = (const float*)d_in[20];
  const float* trans = (const float*)d_in[21];

  float* ws = (float*)d_ws;
  float* preF = ws;                         // 16,777,216 f
  float* preB = ws + 16777216;              // 16,777,216 f
  float* h1s  = ws + 33554432;              //  8,388,608 f (L1 hidden; reused as h2s)
  float* att  = ws + 41943040;              // 16,777,216 f ([w|g] concat)
  float* x0   = ws + 58720256;              //  4,194,304 f (embeddings; reused as feats)
  float* feats = x0;
  float* hx1  = ws + 62914560;              // 32,768 f (64 pairs x 2 parity x 256)
  float* hx2  = ws + 62947328;              // 32,768 f (second scan region)
  int* out = (int*)d_out;

  // NaN-init both exchange regions every launch (replay-safe; NaN fails all band tests)
  hipMemsetAsync(hx1, 0xFF, 2 * 32768 * sizeof(float), stream);
  embed_kernel<<<SEQ * BATCH, 64, 0, stream>>>(inputs, emb, x0);
  gemm_nt<<<dim3(256, 16), 256, 0, stream>>>(x0, w1f_ih, b1f_ih, b1f_hh, preF, 16384, 1024, 256, 1024);
  gemm_nt<<<dim3(256, 16), 256, 0, stream>>>(x0, w1b_ih, b1b_ih, b1b_hh, preB, 16384, 1024, 256, 1024);
  lstm_scan<<<256, 256, 0, stream>>>(preF, preB, w1f_hh, w1b_hh, h1s, hx1);
  gemm_nt<<<dim3(256, 8), 256, 0, stream>>>(h1s, attW, nullptr, nullptr, att, 16384, 512, 512, 1024);
  attention_kernel<<<SEQ, 256, 0, stream>>>(h1s, att);
  gemm_nt<<<dim3(256, 16), 256, 0, stream>>>(att, w2f_ih, b2f_ih, b2f_hh, preF, 16384, 1024, 1024, 1024);
  gemm_nt<<<dim3(256, 16), 256, 0, stream>>>(att, w2b_ih, b2b_ih, b2b_hh, preB, 16384, 1024, 1024, 1024);
  lstm_scan<<<256, 256, 0, stream>>>(preF, preB, w2f_hh, w2b_hh, h1s, hx2);
  gemm_nt<<<dim3(256, 1), 256, 0, stream>>>(h1s, h2t_W, h2t_b, nullptr, feats, 16384, 12, 512, 12);
  viterbi_kernel<<<BATCH, 64, 0, stream>>>(feats, trans, out);
}

// Round 10
// 8332.262 us; speedup vs baseline: 1.1700x; 1.1700x over previous
//
#include <hip/hip_runtime.h>

#define SEQ 512
#define BATCH 32
#define NTAG 12
#define STOP_TAG 11

static __device__ __forceinline__ float sigm(float x) {
  return 1.0f / (1.0f + __expf(-x));
}
static __device__ __forceinline__ float tanh_fast(float x) {
  // exact identity: tanh(x) = 1 - 2/(exp(2x)+1); error only from __expf ulp
  return 1.0f - 2.0f / (1.0f + __expf(2.0f * x));
}

// ---------------- embedding gather: x0[s*32+b][e] = emb[inputs[b][s]][e] ----------------
__global__ __launch_bounds__(64) void embed_kernel(const int* __restrict__ inputs,
                                                   const float* __restrict__ emb,
                                                   float* __restrict__ x0) {
  const int sb = blockIdx.x;          // s*32 + b
  const int s = sb >> 5, b = sb & 31;
  const int tok = inputs[b * SEQ + s];
  const float4* src = (const float4*)(emb + (size_t)tok * 256);
  float4* dst = (float4*)(x0 + (size_t)sb * 256);
  dst[threadIdx.x] = src[threadIdx.x];
}

// ---------------- generic fp32 GEMM: C[M][N] = A[M][K] @ W[N][K]^T (+b1+b2) ----------------
__global__ __launch_bounds__(256) void gemm_nt(const float* __restrict__ A,
                                               const float* __restrict__ W,
                                               const float* __restrict__ b1,
                                               const float* __restrict__ b2,
                                               float* __restrict__ C,
                                               int M, int N, int K, int ldc) {
  __shared__ float aT[16][68];
  __shared__ float wT[16][68];
  const int tid = threadIdx.x;
  const int bm = blockIdx.x * 64;
  const int bn = blockIdx.y * 64;
  const int tm = ((tid >> 4) & 15) << 2;
  const int tn = (tid & 15) << 2;
  const int lr = tid >> 2;
  const int lk = (tid & 3) << 2;
  const bool wok = (bn + lr) < N;
  float acc00 = 0.f, acc01 = 0.f, acc02 = 0.f, acc03 = 0.f;
  float acc10 = 0.f, acc11 = 0.f, acc12 = 0.f, acc13 = 0.f;
  float acc20 = 0.f, acc21 = 0.f, acc22 = 0.f, acc23 = 0.f;
  float acc30 = 0.f, acc31 = 0.f, acc32 = 0.f, acc33 = 0.f;
  for (int k0 = 0; k0 < K; k0 += 16) {
    float4 av = *(const float4*)(A + (size_t)(bm + lr) * K + k0 + lk);
    float4 wv = make_float4(0.f, 0.f, 0.f, 0.f);
    if (wok) wv = *(const float4*)(W + (size_t)(bn + lr) * K + k0 + lk);
    aT[lk + 0][lr] = av.x; aT[lk + 1][lr] = av.y; aT[lk + 2][lr] = av.z; aT[lk + 3][lr] = av.w;
    wT[lk + 0][lr] = wv.x; wT[lk + 1][lr] = wv.y; wT[lk + 2][lr] = wv.z; wT[lk + 3][lr] = wv.w;
    __syncthreads();
#pragma unroll
    for (int k = 0; k < 16; ++k) {
      float4 a4 = *(const float4*)&aT[k][tm];
      float4 w4 = *(const float4*)&wT[k][tn];
      acc00 += a4.x * w4.x; acc01 += a4.x * w4.y; acc02 += a4.x * w4.z; acc03 += a4.x * w4.w;
      acc10 += a4.y * w4.x; acc11 += a4.y * w4.y; acc12 += a4.y * w4.z; acc13 += a4.y * w4.w;
      acc20 += a4.z * w4.x; acc21 += a4.z * w4.y; acc22 += a4.z * w4.z; acc23 += a4.z * w4.w;
      acc30 += a4.w * w4.x; acc31 += a4.w * w4.y; acc32 += a4.w * w4.z; acc33 += a4.w * w4.w;
    }
    __syncthreads();
  }
  float r[4][4] = {{acc00, acc01, acc02, acc03},
                   {acc10, acc11, acc12, acc13},
                   {acc20, acc21, acc22, acc23},
                   {acc30, acc31, acc32, acc33}};
#pragma unroll
  for (int i = 0; i < 4; ++i) {
#pragma unroll
    for (int j = 0; j < 4; ++j) {
      int n = bn + tn + j;
      if (n < N) {
        float v = r[i][j];
        if (b1) v += b1[n];
        if (b2) v += b2[n];
        C[(size_t)(bm + tm + i) * ldc + n] = v;
      }
    }
  }
}

// ---------------- 4-way-split BiLSTM scan with self-tagging exchange ----------------
// grid = 256. bid = q*64 + pair; bid%8 == pair%8 so quarters share an XCD under the %8
// round-robin. Weights register-resident via LDS bounce (R5). Exchange: band-tagged
// values (R7/R8 mechanics): producer stores h + 2*(t&3); consumers poll the data itself
// with single-dword sc0 loads, s_sleep damping from spin>4, agent-scope fallback at
// spin>=16 (wrong-XCD mapping degrades to slow, never hangs).
// R10 drain hygiene (the one change vs R8):
//   - pollers are tid in [64,256) (waves 1-3): ZERO outstanding vmem, so the poll's
//     vmcnt(0) drains only the poll load — no gate-store or prefetch serialization.
//   - wave 0 (non-polling) prefetches next-step pre as float4 after the poll barrier
//     (hidden under FMA+gate) and publishes it via pbuf (LDS) after the gate.
__global__ __launch_bounds__(256, 1) void lstm_scan(const float* __restrict__ pre_f,
                                                    const float* __restrict__ pre_b,
                                                    const float* __restrict__ whh_f,
                                                    const float* __restrict__ whh_b,
                                                    float* __restrict__ hs,   // [SEQ*32][512]
                                                    float* __restrict__ hx) { // [64][2][256], NaN-init
  const int bid = blockIdx.x;
  const int pair = bid & 63;
  const int q = bid >> 6;
  const int dir = pair >> 5;
  const int b = pair & 31;
  const float* __restrict__ pre = dir ? pre_b : pre_f;
  const float* __restrict__ whh = dir ? whh_b : whh_f;
  const int tid = threadIdx.x;
  const int u = tid & 63;
  float* hx_w = hx + pair * 512;                    // [2][256]

  __shared__ float4 stage[8192];   // 128 KB staging, clobbered between rounds
  __shared__ float hbuf[2][256];
  __shared__ float zbuf[256];
  __shared__ float pbuf[256];      // next-step pre, published by wave 0

  // ---- LDS bounce, round 0: k in [0,128) ----
  for (int it = 0; it < 32; ++it) {
    const int id = (it << 8) + tid;
    const int lc = id >> 5;          // local col 0..255
    const int g = id & 31;
    const int gcol = ((lc >> 6) << 8) + (q << 6) + (lc & 63);
    stage[(lc << 5) | (g ^ (lc & 31))] = *((const float4*)(whh + (size_t)gcol * 256) + g);
  }
  __syncthreads();
  float4 wv[64];
#pragma unroll
  for (int g = 0; g < 32; ++g)
    wv[g] = stage[(tid << 5) | (g ^ (tid & 31))];
  __syncthreads();
  // ---- round 1: k in [128,256) overwrites the staging buffer ----
  for (int it = 0; it < 32; ++it) {
    const int id = (it << 8) + tid;
    const int lc = id >> 5;
    const int g = id & 31;
    const int gcol = ((lc >> 6) << 8) + (q << 6) + (lc & 63);
    stage[(lc << 5) | (g ^ (lc & 31))] = *((const float4*)(whh + (size_t)gcol * 256) + 32 + g);
  }
  __syncthreads();
#pragma unroll
  for (int g = 0; g < 32; ++g)
    wv[32 + g] = stage[(tid << 5) | (g ^ (tid & 31))];

  hbuf[0][tid] = 0.0f;
  hbuf[1][tid] = 0.0f;
  float c_reg = 0.0f;               // thread tid<64 owns cell state of unit q*64+tid
  const int sfirst = dir ? (SEQ - 1) : 0;
  if (tid < 64) {                   // preload step-0 pre into pbuf (float4, 4 segments)
    const size_t row = ((size_t)(sfirst * BATCH) + b) * 1024;
    float4 v = *(const float4*)(pre + row + ((tid >> 4) << 8) + (q << 6) + ((tid & 15) << 2));
    *(float4*)&pbuf[((tid >> 4) << 6) + ((tid & 15) << 2)] = v;
  }
  __syncthreads();

  for (int t = 0; t < SEQ; ++t) {
    const int s = dir ? (SEQ - 1 - t) : t;
    if (t > 0) {
      if (tid >= 64) {              // waves 1-3: 192 pollers, clean vmem queues
        const int l = tid - 64;
        const int pq = (q + 1 + (l >> 6)) & 3;
        const int slot = (pq << 6) + (l & 63);
        const float ef = 2.0f * (float)((t - 1) & 3);
        const float* addr = hx_w + ((t - 1) & 1) * 256 + slot;
        float v;
        int spin = 0;
        while (true) {
          if (spin < 16) {
            // L1-bypass, L2-served load; vmcnt(0) drains ONLY this load (no other vmem)
            asm volatile("global_load_dword %0, %1, off sc0\n\t"
                         "s_waitcnt vmcnt(0)"
                         : "=v"(v) : "v"(addr));
          } else {
            // LLC fallback: guaranteed to observe the write-through store
            v = __hip_atomic_load(addr, __ATOMIC_RELAXED, __HIP_MEMORY_SCOPE_AGENT);
          }
          if (__builtin_fabsf(v - ef) <= 1.0f) break;   // NaN/stale-band rejected
          ++spin;
          if (spin > 4) __builtin_amdgcn_s_sleep(1);    // damp poll flood
        }
        hbuf[t & 1][slot] = v - ef;   // exact (Sterbenz)
      }
      __syncthreads();
    }
    // wave 0: issue next-step pre load now (in flight across FMA+gate, off the poll path)
    float4 npv;
    const bool havenp = (tid < 64) && (t + 1 < SEQ);
    if (havenp) {
      const int sn = dir ? (s - 1) : (s + 1);
      const size_t row = ((size_t)(sn * BATCH) + b) * 1024;
      npv = *(const float4*)(pre + row + ((tid >> 4) << 8) + (q << 6) + ((tid & 15) << 2));
    }
    // z[col] = pre + sum_k h[k] * whh[col][k]; 4-way acc split breaks the FMA chain
    float a0 = pbuf[tid], a1 = 0.f, a2 = 0.f, a3 = 0.f;
    const float4* hb = (const float4*)hbuf[t & 1];
#pragma unroll
    for (int g = 0; g < 64; ++g) {
      const float4 h4 = hb[g];      // LDS broadcast
      a0 = fmaf(h4.x, wv[g].x, a0);
      a1 = fmaf(h4.y, wv[g].y, a1);
      a2 = fmaf(h4.z, wv[g].z, a2);
      a3 = fmaf(h4.w, wv[g].w, a3);
    }
    zbuf[tid] = (a0 + a1) + (a2 + a3);
    __syncthreads();
    if (tid < 64) {                 // wave 0: gate combine for unit q*64+u
      const float zi = zbuf[u];
      const float zf = zbuf[64 + u];
      const float zg = zbuf[128 + u];
      const float zo = zbuf[192 + u];
      c_reg = sigm(zf) * c_reg + sigm(zi) * tanh_fast(zg);
      const float h = sigm(zo) * tanh_fast(c_reg);
      // exchange-critical store FIRST (leads the store queue)
      __hip_atomic_store(hx_w + (t & 1) * 256 + (q << 6) + u, h + 2.0f * (float)(t & 3),
                         __ATOMIC_RELAXED, __HIP_MEMORY_SCOPE_AGENT);
      hbuf[(t + 1) & 1][(q << 6) + u] = h;   // ordered before peers' reads by next poll-barrier
      hs[((size_t)(s * BATCH) + b) * 512 + dir * 256 + (q << 6) + u] = h;
    }
    if (havenp)                     // publish next-step pre (readers sync at next barrier)
      *(float4*)&pbuf[((tid >> 4) << 6) + ((tid & 15) << 2)] = npv;
    // no trailing barrier: next iteration's poll-__syncthreads orders zbuf/hbuf/pbuf reuse
  }
}

// ---------------- attention: per time-step s, scores over the batch dim ----------------
__global__ __launch_bounds__(256) void attention_kernel(const float* __restrict__ h1s,
                                                        float* __restrict__ att) {
  const int s = blockIdx.x;
  __shared__ float wl[32][512];   // w rows
  __shared__ float xT[512][36];   // x transposed
  __shared__ float sc[32][33];    // scores / weights
  const int tid = threadIdx.x;
#pragma unroll
  for (int r = 0; r < 16; ++r) {
    int flat = r * 1024 + tid * 4;
    int bb = flat >> 9;
    int d = flat & 511;
    float4 wv = *(const float4*)(att + ((size_t)(s * BATCH) + bb) * 1024 + d);
    *(float4*)&wl[bb][d] = wv;
    float4 xv = *(const float4*)(h1s + ((size_t)(s * BATCH) + bb) * 512 + d);
    xT[d + 0][bb] = xv.x; xT[d + 1][bb] = xv.y; xT[d + 2][bb] = xv.z; xT[d + 3][bb] = xv.w;
  }
  __syncthreads();
  {
    const int i = tid >> 3;
    const int j0 = (tid & 7) << 2;
    float a0 = 0.f, a1 = 0.f, a2 = 0.f, a3 = 0.f;
    for (int k = 0; k < 512; ++k) {
      float wv = wl[i][k];
      float4 x4 = *(const float4*)&xT[k][j0];
      a0 += wv * x4.x; a1 += wv * x4.y; a2 += wv * x4.z; a3 += wv * x4.w;
    }
    sc[i][j0 + 0] = a0; sc[i][j0 + 1] = a1; sc[i][j0 + 2] = a2; sc[i][j0 + 3] = a3;
  }
  __syncthreads();
  if (tid < 32) {
    float m = -3.4e38f;
    for (int j = 0; j < 32; ++j) m = fmaxf(m, sc[tid][j]);
    float sum = 0.f;
    for (int j = 0; j < 32; ++j) { float ev = __expf(sc[tid][j] - m); sc[tid][j] = ev; sum += ev; }
    float inv = 1.0f / sum;
    for (int j = 0; j < 32; ++j) sc[tid][j] *= inv;
  }
  __syncthreads();
  {
    const int i = tid >> 3;
    const int dq = tid & 7;
#pragma unroll
    for (int rep = 0; rep < 8; ++rep) {
      const int d0 = dq * 64 + rep * 8;
      float g0 = 0.f, g1 = 0.f, g2 = 0.f, g3 = 0.f, g4 = 0.f, g5 = 0.f, g6 = 0.f, g7 = 0.f;
      for (int j = 0; j < 32; ++j) {
        float wt = sc[i][j];
        g0 += wt * xT[d0 + 0][j]; g1 += wt * xT[d0 + 1][j];
        g2 += wt * xT[d0 + 2][j]; g3 += wt * xT[d0 + 3][j];
        g4 += wt * xT[d0 + 4][j]; g5 += wt * xT[d0 + 5][j];
        g6 += wt * xT[d0 + 6][j]; g7 += wt * xT[d0 + 7][j];
      }
      float* o = att + ((size_t)(s * BATCH) + i) * 1024 + 512 + d0;
      *(float4*)(o) = make_float4(g0, g1, g2, g3);
      *(float4*)(o + 4) = make_float4(g4, g5, g6, g7);
    }
  }
}

// ---------------- Viterbi decode: one block per batch element ----------------
__global__ __launch_bounds__(64) void viterbi_kernel(const float* __restrict__ feats,
                                                     const float* __restrict__ trans,
                                                     int* __restrict__ out) {
  const int b = blockIdx.x;
  __shared__ float tl[NTAG][NTAG];
  __shared__ float fv[2][NTAG];
  __shared__ unsigned char bp[SEQ][NTAG];
  const int tid = threadIdx.x;
  for (int i = tid; i < NTAG * NTAG; i += 64) tl[i / NTAG][i % NTAG] = trans[i];
  if (tid < NTAG) fv[0][tid] = (tid == 10) ? 0.f : -10000.f;
  __syncthreads();
  for (int t = 0; t < SEQ; ++t) {
    const int cur = t & 1;
    if (tid < NTAG) {
      float m = -3.4e38f;
      int arg = 0;
      for (int p = 0; p < NTAG; ++p) {
        float v = fv[cur][p] + tl[tid][p];
        if (v > m) { m = v; arg = p; }   // strict > == first-max (matches jnp.argmax)
      }
      bp[t][tid] = (unsigned char)arg;
      fv[cur ^ 1][tid] = m + feats[((size_t)t * BATCH + b) * NTAG + tid];
    }
    __syncthreads();
  }
  if (tid == 0) {
    float m = -3.4e38f;
    int tag = 0;
    for (int p = 0; p < NTAG; ++p) {
      float v = fv[0][p] + tl[STOP_TAG][p];
      if (v > m) { m = v; tag = p; }
    }
    for (int t = SEQ - 1; t >= 0; --t) {
      out[b * SEQ + t] = tag;
      tag = bp[t][tag];
    }
  }
}

// ---------------- launch ----------------
extern "C" void kernel_launch(void* const* d_in, const int* in_sizes, int n_in,
                              void* d_out, int out_size, void* d_ws, size_t ws_size,
                              hipStream_t stream) {
  const int* inputs = (const int*)d_in[0];
  const float* emb = (const float*)d_in[1];
  const float* w1f_ih = (const float*)d_in[2];
  const float* w1f_hh = (const float*)d_in[3];
  const float* b1f_ih = (const float*)d_in[4];
  const float* b1f_hh = (const float*)d_in[5];
  const float* w1b_ih = (const float*)d_in[6];
  const float* w1b_hh = (const float*)d_in[7];
  const float* b1b_ih = (const float*)d_in[8];
  const float* b1b_hh = (const float*)d_in[9];
  const float* attW = (const float*)d_in[10];
  const float* w2f_ih = (const float*)d_in[11];
  const float* w2f_hh = (const float*)d_in[12];
  const float* b2f_ih = (const float*)d_in[13];
  const float* b2f_hh = (const float*)d_in[14];
  const float* w2b_ih = (const float*)d_in[15];
  const float* w2b_hh = (const float*)d_in[16];
  const float* b2b_ih = (const float*)d_in[17];
  const float* b2b_hh = (const float*)d_in[18];
  const float* h2t_W = (const float*)d_in[19];
  const float* h2t_b = (const float*)d_in[20];
  const float* trans = (const float*)d_in[21];

  float* ws = (float*)d_ws;
  float* preF = ws;                         // 16,777,216 f
  float* preB = ws + 16777216;              // 16,777,216 f
  float* h1s  = ws + 33554432;              //  8,388,608 f (L1 hidden; reused as h2s)
  float* att  = ws + 41943040;              // 16,777,216 f ([w|g] concat)
  float* x0   = ws + 58720256;              //  4,194,304 f (embeddings; reused as feats)
  float* feats = x0;
  float* hx1  = ws + 62914560;              // 32,768 f (64 pairs x 2 parity x 256)
  float* hx2  = ws + 62947328;              // 32,768 f (second scan region)
  int* out = (int*)d_out;

  // NaN-init both exchange regions every launch (replay-safe; NaN fails all band tests)
  hipMemsetAsync(hx1, 0xFF, 2 * 32768 * sizeof(float), stream);
  embed_kernel<<<SEQ * BATCH, 64, 0, stream>>>(inputs, emb, x0);
  gemm_nt<<<dim3(256, 16), 256, 0, stream>>>(x0, w1f_ih, b1f_ih, b1f_hh, preF, 16384, 1024, 256, 1024);
  gemm_nt<<<dim3(256, 16), 256, 0, stream>>>(x0, w1b_ih, b1b_ih, b1b_hh, preB, 16384, 1024, 256, 1024);
  lstm_scan<<<256, 256, 0, stream>>>(preF, preB, w1f_hh, w1b_hh, h1s, hx1);
  gemm_nt<<<dim3(256, 8), 256, 0, stream>>>(h1s, attW, nullptr, nullptr, att, 16384, 512, 512, 1024);
  attention_kernel<<<SEQ, 256, 0, stream>>>(h1s, att);
  gemm_nt<<<dim3(256, 16), 256, 0, stream>>>(att, w2f_ih, b2f_ih, b2f_hh, preF, 16384, 1024, 1024, 1024);
  gemm_nt<<<dim3(256, 16), 256, 0, stream>>>(att, w2b_ih, b2b_ih, b2b_hh, preB, 16384, 1024, 1024, 1024);
  lstm_scan<<<256, 256, 0, stream>>>(preF, preB, w2f_hh, w2b_hh, h1s, hx2);
  gemm_nt<<<dim3(256, 1), 256, 0, stream>>>(h1s, h2t_W, h2t_b, nullptr, feats, 16384, 12, 512, 12);
  viterbi_kernel<<<BATCH, 64, 0, stream>>>(feats, trans, out);
}

// Round 11
// 5997.889 us; speedup vs baseline: 1.6253x; 1.3892x over previous
//
#include <hip/hip_runtime.h>

#define SEQ 512
#define BATCH 32
#define NTAG 12
#define STOP_TAG 11

static __device__ __forceinline__ float sigm(float x) {
  return 1.0f / (1.0f + __expf(-x));
}
static __device__ __forceinline__ float tanh_fast(float x) {
  // exact identity: tanh(x) = 1 - 2/(exp(2x)+1); error only from __expf ulp
  return 1.0f - 2.0f / (1.0f + __expf(2.0f * x));
}

// ---------------- embedding gather: x0[s*32+b][e] = emb[inputs[b][s]][e] ----------------
__global__ __launch_bounds__(64) void embed_kernel(const int* __restrict__ inputs,
                                                   const float* __restrict__ emb,
                                                   float* __restrict__ x0) {
  const int sb = blockIdx.x;          // s*32 + b
  const int s = sb >> 5, b = sb & 31;
  const int tok = inputs[b * SEQ + s];
  const float4* src = (const float4*)(emb + (size_t)tok * 256);
  float4* dst = (float4*)(x0 + (size_t)sb * 256);
  dst[threadIdx.x] = src[threadIdx.x];
}

// ---------------- fp32 GEMM, 128x128 tile, 8x8/thread: C = A[M][K] @ W[N][K]^T (+b1+b2) ----------------
// M, N multiples of 128. 256 threads. BK=8. LDS 8.5 KB. VALU-bound: 4 b128 LDS reads
// per 64 FMAs (vs 2 per 16 in the old 64x64 tile).
__global__ __launch_bounds__(256) void gemm128(const float* __restrict__ A,
                                               const float* __restrict__ W,
                                               const float* __restrict__ b1,
                                               const float* __restrict__ b2,
                                               float* __restrict__ C,
                                               int M, int N, int K) {
  __shared__ float aT[8][132];
  __shared__ float wT[8][132];
  const int tid = threadIdx.x;
  const int bm = blockIdx.x * 128;
  const int bn = blockIdx.y * 128;
  const int tm = (tid >> 4) << 3;   // 0..120
  const int tn = (tid & 15) << 3;   // 0..120
  const int lr = tid >> 1;          // tile row 0..127
  const int lk = (tid & 1) << 2;    // k offset 0 or 4
  const float* __restrict__ aSrc = A + (size_t)(bm + lr) * K + lk;
  const float* __restrict__ wSrc = W + (size_t)(bn + lr) * K + lk;
  float acc[8][8] = {{0.f}};
  for (int k0 = 0; k0 < K; k0 += 8) {
    const float4 av = *(const float4*)(aSrc + k0);
    const float4 wv = *(const float4*)(wSrc + k0);
    __syncthreads();                // previous iter's LDS reads complete
    aT[lk + 0][lr] = av.x; aT[lk + 1][lr] = av.y; aT[lk + 2][lr] = av.z; aT[lk + 3][lr] = av.w;
    wT[lk + 0][lr] = wv.x; wT[lk + 1][lr] = wv.y; wT[lk + 2][lr] = wv.z; wT[lk + 3][lr] = wv.w;
    __syncthreads();
#pragma unroll
    for (int k = 0; k < 8; ++k) {
      const float4 a0 = *(const float4*)&aT[k][tm];
      const float4 a1 = *(const float4*)&aT[k][tm + 4];
      const float4 w0 = *(const float4*)&wT[k][tn];
      const float4 w1 = *(const float4*)&wT[k][tn + 4];
      const float a[8] = {a0.x, a0.y, a0.z, a0.w, a1.x, a1.y, a1.z, a1.w};
      const float w[8] = {w0.x, w0.y, w0.z, w0.w, w1.x, w1.y, w1.z, w1.w};
#pragma unroll
      for (int i = 0; i < 8; ++i)
#pragma unroll
        for (int j = 0; j < 8; ++j)
          acc[i][j] = fmaf(a[i], w[j], acc[i][j]);
    }
  }
  float bias[8];
#pragma unroll
  for (int j = 0; j < 8; ++j) {
    const int n = bn + tn + j;
    bias[j] = (b1 ? b1[n] : 0.f) + (b2 ? b2[n] : 0.f);
  }
#pragma unroll
  for (int i = 0; i < 8; ++i) {
    float* row = C + (size_t)(bm + tm + i) * N + bn + tn;
    *(float4*)(row) = make_float4(acc[i][0] + bias[0], acc[i][1] + bias[1],
                                  acc[i][2] + bias[2], acc[i][3] + bias[3]);
    *(float4*)(row + 4) = make_float4(acc[i][4] + bias[4], acc[i][5] + bias[5],
                                      acc[i][6] + bias[6], acc[i][7] + bias[7]);
  }
}

// ---------------- generic fp32 GEMM (64x64 tile) — used only for the ragged N=12 feats GEMM ----------------
__global__ __launch_bounds__(256) void gemm_nt(const float* __restrict__ A,
                                               const float* __restrict__ W,
                                               const float* __restrict__ b1,
                                               const float* __restrict__ b2,
                                               float* __restrict__ C,
                                               int M, int N, int K, int ldc) {
  __shared__ float aT[16][68];
  __shared__ float wT[16][68];
  const int tid = threadIdx.x;
  const int bm = blockIdx.x * 64;
  const int bn = blockIdx.y * 64;
  const int tm = ((tid >> 4) & 15) << 2;
  const int tn = (tid & 15) << 2;
  const int lr = tid >> 2;
  const int lk = (tid & 3) << 2;
  const bool wok = (bn + lr) < N;
  float acc00 = 0.f, acc01 = 0.f, acc02 = 0.f, acc03 = 0.f;
  float acc10 = 0.f, acc11 = 0.f, acc12 = 0.f, acc13 = 0.f;
  float acc20 = 0.f, acc21 = 0.f, acc22 = 0.f, acc23 = 0.f;
  float acc30 = 0.f, acc31 = 0.f, acc32 = 0.f, acc33 = 0.f;
  for (int k0 = 0; k0 < K; k0 += 16) {
    float4 av = *(const float4*)(A + (size_t)(bm + lr) * K + k0 + lk);
    float4 wv = make_float4(0.f, 0.f, 0.f, 0.f);
    if (wok) wv = *(const float4*)(W + (size_t)(bn + lr) * K + k0 + lk);
    aT[lk + 0][lr] = av.x; aT[lk + 1][lr] = av.y; aT[lk + 2][lr] = av.z; aT[lk + 3][lr] = av.w;
    wT[lk + 0][lr] = wv.x; wT[lk + 1][lr] = wv.y; wT[lk + 2][lr] = wv.z; wT[lk + 3][lr] = wv.w;
    __syncthreads();
#pragma unroll
    for (int k = 0; k < 16; ++k) {
      float4 a4 = *(const float4*)&aT[k][tm];
      float4 w4 = *(const float4*)&wT[k][tn];
      acc00 += a4.x * w4.x; acc01 += a4.x * w4.y; acc02 += a4.x * w4.z; acc03 += a4.x * w4.w;
      acc10 += a4.y * w4.x; acc11 += a4.y * w4.y; acc12 += a4.y * w4.z; acc13 += a4.y * w4.w;
      acc20 += a4.z * w4.x; acc21 += a4.z * w4.y; acc22 += a4.z * w4.z; acc23 += a4.z * w4.w;
      acc30 += a4.w * w4.x; acc31 += a4.w * w4.y; acc32 += a4.w * w4.z; acc33 += a4.w * w4.w;
    }
    __syncthreads();
  }
  float r[4][4] = {{acc00, acc01, acc02, acc03},
                   {acc10, acc11, acc12, acc13},
                   {acc20, acc21, acc22, acc23},
                   {acc30, acc31, acc32, acc33}};
#pragma unroll
  for (int i = 0; i < 4; ++i) {
#pragma unroll
    for (int j = 0; j < 4; ++j) {
      int n = bn + tn + j;
      if (n < N) {
        float v = r[i][j];
        if (b1) v += b1[n];
        if (b2) v += b2[n];
        C[(size_t)(bm + tm + i) * ldc + n] = v;
      }
    }
  }
}

// ---------------- 4-way-split BiLSTM scan with self-tagging exchange (R8 verbatim) ----------------
// grid = 256. bid = q*64 + pair; bid%8 == pair%8 so quarters share an XCD under the %8
// round-robin. Weights register-resident via LDS bounce (R5). Exchange: band-tagged
// values: producer stores h + 2*(t&3); consumers poll the data itself with single-dword
// sc0 loads, s_sleep damping from spin>4, agent-scope fallback at spin>=16.
// NOTE (R9/R10 lesson): pollers on waves 0-2 with np prefetch issued at loop top IS the
// empirical optimum; both "drain hygiene" restructures regressed 30-60%. Do not touch.
__global__ __launch_bounds__(256, 1) void lstm_scan(const float* __restrict__ pre_f,
                                                    const float* __restrict__ pre_b,
                                                    const float* __restrict__ whh_f,
                                                    const float* __restrict__ whh_b,
                                                    float* __restrict__ hs,   // [SEQ*32][512]
                                                    float* __restrict__ hx) { // [64][2][256], NaN-init
  const int bid = blockIdx.x;
  const int pair = bid & 63;
  const int q = bid >> 6;
  const int dir = pair >> 5;
  const int b = pair & 31;
  const float* __restrict__ pre = dir ? pre_b : pre_f;
  const float* __restrict__ whh = dir ? whh_b : whh_f;
  const int tid = threadIdx.x;
  const int u = tid & 63;
  const int col = (tid >> 6) * 256 + (q << 6) + u;
  float* hx_w = hx + pair * 512;                    // [2][256]

  __shared__ float4 stage[8192];   // 128 KB staging, clobbered between rounds
  __shared__ float hbuf[2][256];
  __shared__ float zbuf[256];

  // ---- LDS bounce, round 0: k in [0,128) ----
  for (int it = 0; it < 32; ++it) {
    const int id = (it << 8) + tid;
    const int lc = id >> 5;          // local col 0..255
    const int g = id & 31;
    const int gcol = ((lc >> 6) << 8) + (q << 6) + (lc & 63);
    stage[(lc << 5) | (g ^ (lc & 31))] = *((const float4*)(whh + (size_t)gcol * 256) + g);
  }
  __syncthreads();
  float4 wv[64];
#pragma unroll
  for (int g = 0; g < 32; ++g)
    wv[g] = stage[(tid << 5) | (g ^ (tid & 31))];
  __syncthreads();
  // ---- round 1: k in [128,256) overwrites the staging buffer ----
  for (int it = 0; it < 32; ++it) {
    const int id = (it << 8) + tid;
    const int lc = id >> 5;
    const int g = id & 31;
    const int gcol = ((lc >> 6) << 8) + (q << 6) + (lc & 63);
    stage[(lc << 5) | (g ^ (lc & 31))] = *((const float4*)(whh + (size_t)gcol * 256) + 32 + g);
  }
  __syncthreads();
#pragma unroll
  for (int g = 0; g < 32; ++g)
    wv[32 + g] = stage[(tid << 5) | (g ^ (tid & 31))];

  hbuf[0][tid] = 0.0f;
  hbuf[1][tid] = 0.0f;
  float c_reg = 0.0f;               // thread tid<64 owns cell state of unit q*64+tid
  const int sfirst = dir ? (SEQ - 1) : 0;
  float p = pre[((size_t)(sfirst * BATCH) + b) * 1024 + col];
  __syncthreads();

  for (int t = 0; t < SEQ; ++t) {
    const int s = dir ? (SEQ - 1 - t) : t;
    float np = 0.0f;                // prefetch next step's pre
    if (t + 1 < SEQ) {
      const int sn = dir ? (s - 1) : (s + 1);
      np = pre[((size_t)(sn * BATCH) + b) * 1024 + col];
    }
    if (t > 0) {
      if (tid < 192) {              // waves 0-2: poll the 192 peer h values (self-tagged)
        const int pq = (q + 1 + (tid >> 6)) & 3;
        const int slot = (pq << 6) + (tid & 63);
        const float ef = 2.0f * (float)((t - 1) & 3);
        const float* addr = hx_w + ((t - 1) & 1) * 256 + slot;
        float v;
        int spin = 0;
        while (true) {
          if (spin < 16) {
            // L1-bypass, L2-served load (XCD-local fast path)
            asm volatile("global_load_dword %0, %1, off sc0\n\t"
                         "s_waitcnt vmcnt(0)"
                         : "=v"(v) : "v"(addr));
          } else {
            // LLC fallback: guaranteed to observe the write-through store
            v = __hip_atomic_load(addr, __ATOMIC_RELAXED, __HIP_MEMORY_SCOPE_AGENT);
          }
          if (__builtin_fabsf(v - ef) <= 1.0f) break;   // NaN/stale-band rejected
          ++spin;
          if (spin > 4) __builtin_amdgcn_s_sleep(1);    // damp poll flood
        }
        hbuf[t & 1][slot] = v - ef;   // exact (Sterbenz)
      }
      __syncthreads();
    }
    // z[col] = pre + sum_k h[k] * whh[col][k]; 4-way acc split breaks the FMA chain
    float a0 = p, a1 = 0.f, a2 = 0.f, a3 = 0.f;
    const float4* hb = (const float4*)hbuf[t & 1];
#pragma unroll
    for (int g = 0; g < 64; ++g) {
      const float4 h4 = hb[g];      // LDS broadcast
      a0 = fmaf(h4.x, wv[g].x, a0);
      a1 = fmaf(h4.y, wv[g].y, a1);
      a2 = fmaf(h4.z, wv[g].z, a2);
      a3 = fmaf(h4.w, wv[g].w, a3);
    }
    zbuf[tid] = (a0 + a1) + (a2 + a3);
    __syncthreads();
    if (tid < 64) {                 // wave 0: gate combine for unit q*64+u
      const float zi = zbuf[u];
      const float zf = zbuf[64 + u];
      const float zg = zbuf[128 + u];
      const float zo = zbuf[192 + u];
      c_reg = sigm(zf) * c_reg + sigm(zi) * tanh_fast(zg);
      const float h = sigm(zo) * tanh_fast(c_reg);
      // exchange-critical store FIRST (leads the store queue)
      __hip_atomic_store(hx_w + (t & 1) * 256 + (q << 6) + u, h + 2.0f * (float)(t & 3),
                         __ATOMIC_RELAXED, __HIP_MEMORY_SCOPE_AGENT);
      hbuf[(t + 1) & 1][(q << 6) + u] = h;   // ordered before peers' reads by next poll-barrier
      hs[((size_t)(s * BATCH) + b) * 512 + dir * 256 + (q << 6) + u] = h;
    }
    // no trailing barrier: next iteration's poll-__syncthreads orders zbuf/hbuf reuse
    p = np;
  }
}

// ---------------- attention: per time-step s, scores over the batch dim ----------------
__global__ __launch_bounds__(256) void attention_kernel(const float* __restrict__ h1s,
                                                        float* __restrict__ att) {
  const int s = blockIdx.x;
  __shared__ float wl[32][512];   // w rows
  __shared__ float xT[512][36];   // x transposed
  __shared__ float sc[32][33];    // scores / weights
  const int tid = threadIdx.x;
#pragma unroll
  for (int r = 0; r < 16; ++r) {
    int flat = r * 1024 + tid * 4;
    int bb = flat >> 9;
    int d = flat & 511;
    float4 wv = *(const float4*)(att + ((size_t)(s * BATCH) + bb) * 1024 + d);
    *(float4*)&wl[bb][d] = wv;
    float4 xv = *(const float4*)(h1s + ((size_t)(s * BATCH) + bb) * 512 + d);
    xT[d + 0][bb] = xv.x; xT[d + 1][bb] = xv.y; xT[d + 2][bb] = xv.z; xT[d + 3][bb] = xv.w;
  }
  __syncthreads();
  {
    const int i = tid >> 3;
    const int j0 = (tid & 7) << 2;
    float a0 = 0.f, a1 = 0.f, a2 = 0.f, a3 = 0.f;
    for (int k = 0; k < 512; ++k) {
      float wv = wl[i][k];
      float4 x4 = *(const float4*)&xT[k][j0];
      a0 += wv * x4.x; a1 += wv * x4.y; a2 += wv * x4.z; a3 += wv * x4.w;
    }
    sc[i][j0 + 0] = a0; sc[i][j0 + 1] = a1; sc[i][j0 + 2] = a2; sc[i][j0 + 3] = a3;
  }
  __syncthreads();
  if (tid < 32) {
    float m = -3.4e38f;
    for (int j = 0; j < 32; ++j) m = fmaxf(m, sc[tid][j]);
    float sum = 0.f;
    for (int j = 0; j < 32; ++j) { float ev = __expf(sc[tid][j] - m); sc[tid][j] = ev; sum += ev; }
    float inv = 1.0f / sum;
    for (int j = 0; j < 32; ++j) sc[tid][j] *= inv;
  }
  __syncthreads();
  {
    const int i = tid >> 3;
    const int dq = tid & 7;
#pragma unroll
    for (int rep = 0; rep < 8; ++rep) {
      const int d0 = dq * 64 + rep * 8;
      float g0 = 0.f, g1 = 0.f, g2 = 0.f, g3 = 0.f, g4 = 0.f, g5 = 0.f, g6 = 0.f, g7 = 0.f;
      for (int j = 0; j < 32; ++j) {
        float wt = sc[i][j];
        g0 += wt * xT[d0 + 0][j]; g1 += wt * xT[d0 + 1][j];
        g2 += wt * xT[d0 + 2][j]; g3 += wt * xT[d0 + 3][j];
        g4 += wt * xT[d0 + 4][j]; g5 += wt * xT[d0 + 5][j];
        g6 += wt * xT[d0 + 6][j]; g7 += wt * xT[d0 + 7][j];
      }
      float* o = att + ((size_t)(s * BATCH) + i) * 1024 + 512 + d0;
      *(float4*)(o) = make_float4(g0, g1, g2, g3);
      *(float4*)(o + 4) = make_float4(g4, g5, g6, g7);
    }
  }
}

// ---------------- Viterbi decode: one block per batch element ----------------
__global__ __launch_bounds__(64) void viterbi_kernel(const float* __restrict__ feats,
                                                     const float* __restrict__ trans,
                                                     int* __restrict__ out) {
  const int b = blockIdx.x;
  __shared__ float tl[NTAG][NTAG];
  __shared__ float fv[2][NTAG];
  __shared__ unsigned char bp[SEQ][NTAG];
  const int tid = threadIdx.x;
  for (int i = tid; i < NTAG * NTAG; i += 64) tl[i / NTAG][i % NTAG] = trans[i];
  if (tid < NTAG) fv[0][tid] = (tid == 10) ? 0.f : -10000.f;
  __syncthreads();
  for (int t = 0; t < SEQ; ++t) {
    const int cur = t & 1;
    if (tid < NTAG) {
      float m = -3.4e38f;
      int arg = 0;
      for (int p = 0; p < NTAG; ++p) {
        float v = fv[cur][p] + tl[tid][p];
        if (v > m) { m = v; arg = p; }   // strict > == first-max (matches jnp.argmax)
      }
      bp[t][tid] = (unsigned char)arg;
      fv[cur ^ 1][tid] = m + feats[((size_t)t * BATCH + b) * NTAG + tid];
    }
    __syncthreads();
  }
  if (tid == 0) {
    float m = -3.4e38f;
    int tag = 0;
    for (int p = 0; p < NTAG; ++p) {
      float v = fv[0][p] + tl[STOP_TAG][p];
      if (v > m) { m = v; tag = p; }
    }
    for (int t = SEQ - 1; t >= 0; --t) {
      out[b * SEQ + t] = tag;
      tag = bp[t][tag];
    }
  }
}

// ---------------- launch ----------------
extern "C" void kernel_launch(void* const* d_in, const int* in_sizes, int n_in,
                              void* d_out, int out_size, void* d_ws, size_t ws_size,
                              hipStream_t stream) {
  const int* inputs = (const int*)d_in[0];
  const float* emb = (const float*)d_in[1];
  const float* w1f_ih = (const float*)d_in[2];
  const float* w1f_hh = (const float*)d_in[3];
  const float* b1f_ih = (const float*)d_in[4];
  const float* b1f_hh = (const float*)d_in[5];
  const float* w1b_ih = (const float*)d_in[6];
  const float* w1b_hh = (const float*)d_in[7];
  const float* b1b_ih = (const float*)d_in[8];
  const float* b1b_hh = (const float*)d_in[9];
  const float* attW = (const float*)d_in[10];
  const float* w2f_ih = (const float*)d_in[11];
  const float* w2f_hh = (const float*)d_in[12];
  const float* b2f_ih = (const float*)d_in[13];
  const float* b2f_hh = (const float*)d_in[14];
  const float* w2b_ih = (const float*)d_in[15];
  const float* w2b_hh = (const float*)d_in[16];
  const float* b2b_ih = (const float*)d_in[17];
  const float* b2b_hh = (const float*)d_in[18];
  const float* h2t_W = (const float*)d_in[19];
  const float* h2t_b = (const float*)d_in[20];
  const float* trans = (const float*)d_in[21];

  float* ws = (float*)d_ws;
  float* preF = ws;                         // 16,777,216 f
  float* preB = ws + 16777216;              // 16,777,216 f
  float* h1s  = ws + 33554432;              //  8,388,608 f (L1 hidden; reused as h2s)
  float* att  = ws + 41943040;              // 16,777,216 f ([w|g] concat)
  float* x0   = ws + 58720256;              //  4,194,304 f (embeddings; reused as feats)
  float* feats = x0;
  float* hx1  = ws + 62914560;              // 32,768 f (64 pairs x 2 parity x 256)
  float* hx2  = ws + 62947328;              // 32,768 f (second scan region)
  int* out = (int*)d_out;

  // NaN-init both exchange regions every launch (replay-safe; NaN fails all band tests)
  hipMemsetAsync(hx1, 0xFF, 2 * 32768 * sizeof(float), stream);
  embed_kernel<<<SEQ * BATCH, 64, 0, stream>>>(inputs, emb, x0);
  gemm128<<<dim3(128, 8), 256, 0, stream>>>(x0, w1f_ih, b1f_ih, b1f_hh, preF, 16384, 1024, 256);
  gemm128<<<dim3(128, 8), 256, 0, stream>>>(x0, w1b_ih, b1b_ih, b1b_hh, preB, 16384, 1024, 256);
  lstm_scan<<<256, 256, 0, stream>>>(preF, preB, w1f_hh, w1b_hh, h1s, hx1);
  gemm_nt<<<dim3(256, 8), 256, 0, stream>>>(h1s, attW, nullptr, nullptr, att, 16384, 512, 512, 1024);
  attention_kernel<<<SEQ, 256, 0, stream>>>(h1s, att);
  gemm128<<<dim3(128, 8), 256, 0, stream>>>(att, w2f_ih, b2f_ih, b2f_hh, preF, 16384, 1024, 1024);
  gemm128<<<dim3(128, 8), 256, 0, stream>>>(att, w2b_ih, b2b_ih, b2b_hh, preB, 16384, 1024, 1024);
  lstm_scan<<<256, 256, 0, stream>>>(preF, preB, w2f_hh, w2b_hh, h1s, hx2);
  gemm_nt<<<dim3(256, 1), 256, 0, stream>>>(h1s, h2t_W, h2t_b, nullptr, feats, 16384, 12, 512, 12);
  viterbi_kernel<<<BATCH, 64, 0, stream>>>(feats, trans, out);
}